// Round 5
// baseline (223.447 us; speedup 1.0000x reference)
//
#include <hip/hip_runtime.h>
#include <hip/hip_cooperative_groups.h>

namespace cg = cooperative_groups;

// Problem constants (fixed by reference): S=256, B=64, D=1024, T=64
#define SLEN 256
#define NB   64
#define ND   1024
#define NT   64
// BOS=0, EOS=1, PAD=2

typedef float f32x4  __attribute__((ext_vector_type(4)));
typedef short bf16x8 __attribute__((ext_vector_type(8)));
typedef unsigned int u32;
typedef u32 u32x2 __attribute__((ext_vector_type(2)));
typedef u32 u32x4 __attribute__((ext_vector_type(4)));

__device__ __forceinline__ u32 cvt_pk_bf16(float lo, float hi) {
  u32 r;
  asm("v_cvt_pk_bf16_f32 %0, %1, %2" : "=v"(r) : "v"(lo), "v"(hi));
  return r;
}

__device__ __forceinline__ unsigned short f2bf(float f) {   // RNE, f finite
  u32 u = __float_as_uint(f);
  return (unsigned short)((u + 0x7FFFu + ((u >> 16) & 1u)) >> 16);
}

__device__ __forceinline__ bf16x8 pack_bf16x8(f32x4 a, f32x4 b) {
  union { u32 u[4]; bf16x8 v; } r;
  r.u[0] = cvt_pk_bf16(a.x, a.y);
  r.u[1] = cvt_pk_bf16(a.z, a.w);
  r.u[2] = cvt_pk_bf16(b.x, b.y);
  r.u[3] = cvt_pk_bf16(b.z, b.w);
  return r.v;
}

// ---------------------------------------------------------------------------
// Single cooperative kernel, 512 blocks x 256 threads (2 blocks/CU resident).
// Phase 0: W -> bf16 frag-stream (blocks 0..255); E'^T hi/lo table + out=0
//          (block 256).
// Phase 1: emit GEMM, 2-way K-split per 16-row strip (8 waves/CU), LDS
//          combine; epilogue writes xbuf = bf16(exp(emit+bias)).
// Phase 2: 8 chunk-product matrices per batch (32 steps each), R3/R4-proven
//          MFMA recurrence; wave 0 adds the chunk's gold-score slice.
// Phase 3: per-batch 8-apply alpha scan (blocks 0..63, wave 0) + atomicAdd.
// ---------------------------------------------------------------------------
__global__ __launch_bounds__(256, 2) void mega(
    const float* __restrict__ F, const int* __restrict__ tags,
    const int* __restrict__ seq, const float* __restrict__ W,
    const float* __restrict__ bias, const float* __restrict__ trans,
    unsigned short* __restrict__ xbuf, unsigned short* __restrict__ Wb3,
    u32* __restrict__ Ebuf, unsigned short* __restrict__ Gout,
    float* __restrict__ out)
{
  cg::grid_group grid = cg::this_grid();
  __shared__ union ShU {
    float comb[4][64][17];   // phase 1 K-split combine (padded, 17.4 KB)
    float trs[64 * 68];      // phase 2 transpose / phase 3 elds
  } sh;

  const int blk = blockIdx.x;        // 0..511
  const int tid = threadIdx.x;
  const int w   = tid >> 6;          // wave 0..3
  const int l   = tid & 63;
  const int q   = l >> 4, c = l & 15;

  // ============================ phase 0: prep ============================
  if (blk < 256) {
    int o  = blk * 256 + tid;        // 0..65535
    int e  = o & 7;
    int ll = (o >> 3) & 63;
    int f  = (o >> 9) & 3;
    int k0 = o >> 11;
    int t  = f * 16 + (ll & 15);
    int k  = k0 * 32 + ((ll >> 4) << 3) + e;
    Wb3[o] = f2bf(W[t * ND + k]);
  } else if (blk == 256) {
    if (tid == 0) out[0] = 0.f;
    const int wd = tid >> 6;         // word 0..3
#pragma unroll
    for (int mt = 0; mt < 4; ++mt)
#pragma unroll
      for (int kf = 0; kf < 2; ++kf) {
        float v0 = __expf(trans[(32 * kf + 8 * q + 2 * wd)     * NT + 16 * mt + c]) * 0.015625f;
        float v1 = __expf(trans[(32 * kf + 8 * q + 2 * wd + 1) * NT + 16 * mt + c]) * 0.015625f;
        u32 u0 = __float_as_uint(v0), u1 = __float_as_uint(v1);
        float h0 = __uint_as_float((u0 + 0x7FFFu + ((u0 >> 16) & 1u)) & 0xFFFF0000u);
        float h1 = __uint_as_float((u1 + 0x7FFFu + ((u1 >> 16) & 1u)) & 0xFFFF0000u);
        Ebuf[((mt * 2 + kf) * 2 + 0) * 256 + l * 4 + wd] = cvt_pk_bf16(h0, h1);
        Ebuf[((mt * 2 + kf) * 2 + 1) * 256 + l * 4 + wd] = cvt_pk_bf16(v0 - h0, v1 - h1);
      }
  }

  grid.sync();

  // ============================ phase 1: emit ============================
  {
    const int strip = blk * 2 + (w >> 1);   // 0..1023 (16-row strip)
    const int kh    = w & 1;                // K half: [kh*512, kh*512+512)
    const float* arow = F + (size_t)(strip * 16 + c) * ND + kh * 512 + q * 8;
    const bf16x8* bptr = reinterpret_cast<const bf16x8*>(Wb3) + l;

    f32x4 acc0 = {0.f, 0.f, 0.f, 0.f};
    f32x4 acc1 = acc0, acc2 = acc0, acc3 = acc0;

    for (int g = 0; g < 16; g += 4) {
      f32x4  a[4][2];
      bf16x8 bb[4][4];
#pragma unroll
      for (int qq = 0; qq < 4; ++qq) {
        a[qq][0] = *(const f32x4*)(arow + (g + qq) * 32);
        a[qq][1] = *(const f32x4*)(arow + (g + qq) * 32 + 4);
#pragma unroll
        for (int f = 0; f < 4; ++f)
          bb[qq][f] = bptr[((kh * 16 + g + qq) * 4 + f) * 64];
      }
#pragma unroll
      for (int qq = 0; qq < 4; ++qq) {
        bf16x8 af = pack_bf16x8(a[qq][0], a[qq][1]);
        acc0 = __builtin_amdgcn_mfma_f32_16x16x32_bf16(af, bb[qq][0], acc0, 0, 0, 0);
        acc1 = __builtin_amdgcn_mfma_f32_16x16x32_bf16(af, bb[qq][1], acc1, 0, 0, 0);
        acc2 = __builtin_amdgcn_mfma_f32_16x16x32_bf16(af, bb[qq][2], acc2, 0, 0, 0);
        acc3 = __builtin_amdgcn_mfma_f32_16x16x32_bf16(af, bb[qq][3], acc3, 0, 0, 0);
      }
    }

#pragma unroll
    for (int r = 0; r < 4; ++r) {
      sh.comb[w][l][r]      = acc0[r];
      sh.comb[w][l][4 + r]  = acc1[r];
      sh.comb[w][l][8 + r]  = acc2[r];
      sh.comb[w][l][12 + r] = acc3[r];
    }
    __syncthreads();
    if (kh == 0) {
#pragma unroll
      for (int r = 0; r < 4; ++r) {
        acc0[r] += sh.comb[w ^ 1][l][r];
        acc1[r] += sh.comb[w ^ 1][l][4 + r];
        acc2[r] += sh.comb[w ^ 1][l][8 + r];
        acc3[r] += sh.comb[w ^ 1][l][12 + r];
      }
      const float bv0 = bias[c], bv1 = bias[16 + c], bv2 = bias[32 + c], bv3 = bias[48 + c];
      unsigned short* op = xbuf + (size_t)(strip * 16 + q * 4) * NT + c;
#pragma unroll
      for (int r = 0; r < 4; ++r) {
        op[r * NT +  0] = f2bf(__expf(acc0[r] + bv0));
        op[r * NT + 16] = f2bf(__expf(acc1[r] + bv1));
        op[r * NT + 32] = f2bf(__expf(acc2[r] + bv2));
        op[r * NT + 48] = f2bf(__expf(acc3[r] + bv3));
      }
    }
  }

  grid.sync();

  // ========================= phase 2: chunk products =========================
  {
    const int b = blk >> 3;          // batch
    const int k = blk & 7;           // chunk (32 steps)
    const int L = seq[b];            // in [2,256]

    // ---- gold slice: s in [32k, 32k+32) ∩ [0,L), wave 0 lanes 0..31 ----
    if (w == 0) {
      float gp = 0.f;
      int s = 32 * k + (l & 31);
      if (l < 32 && s < L) {
        int tg = tags[s * NB + b];
        int nx = (s + 1 < SLEN) ? tags[(s + 1) * NB + b] : 2;
        float xv = __uint_as_float((u32)xbuf[(size_t)(s * NB + b) * NT + tg] << 16);
        gp = __logf(xv) + trans[tg * NT + nx];
      }
      gp += __shfl_xor(gp, 1, 64);
      gp += __shfl_xor(gp, 2, 64);
      gp += __shfl_xor(gp, 4, 64);
      gp += __shfl_xor(gp, 8, 64);
      gp += __shfl_xor(gp, 16, 64);
      if (l == 0) atomicAdd(out, -gp);
    }

    // ---- E'^T fragments from table (hi + lo) ----
    union uf { u32x4 u; bf16x8 v; };
    uf eh[4][2], el[4][2];
#pragma unroll
    for (int mt = 0; mt < 4; ++mt)
#pragma unroll
      for (int kf = 0; kf < 2; ++kf) {
        eh[mt][kf].u = *(const u32x4*)(Ebuf + ((mt * 2 + kf) * 2 + 0) * 256 + l * 4);
        el[mt][kf].u = *(const u32x4*)(Ebuf + ((mt * 2 + kf) * 2 + 1) * 256 + l * 4);
      }

    // ---- G = I (this wave's 16-column tile): G[16mt+4q+r][16w+c] ----
    f32x4 g[4];
#pragma unroll
    for (int mt = 0; mt < 4; ++mt) {
      f32x4 z = {0.f, 0.f, 0.f, 0.f};
      int r = c - 4 * q;
      if (mt == w && r >= 0 && r < 4) z[r] = 1.0f;
      g[mt] = z;
    }

    int tbeg = 32 * k; if (tbeg < 1) tbeg = 1;
    int tend = 32 * k + 32; if (tend > L) tend = L;

    const unsigned short* xb = xbuf + (size_t)b * NT + 4 * q;

#define SWAPQ(A, B) do {                                                  \
    asm("v_permlane32_swap_b32 %0, %1" : "+v"(A), "+v"(B));               \
    asm("v_permlane16_swap_b32 %0, %1" : "+v"(A), "+v"(B));               \
  } while (0)

    if (tbeg < tend) {
      u32x2 xs[4], xn[4];
#pragma unroll
      for (int mt = 0; mt < 4; ++mt)
        xs[mt] = *(const u32x2*)(xb + (size_t)tbeg * (NB * NT) + 16 * mt);

      for (int t = tbeg; t < tend; ++t) {
#pragma unroll
        for (int mt = 0; mt < 4; ++mt)
          xn[mt] = *(const u32x2*)(xb + (size_t)(t + 1) * (NB * NT) + 16 * mt);

        u32 p[4][2];
#pragma unroll
        for (int mt = 0; mt < 4; ++mt) {
          u32 w0 = xs[mt].x, w1 = xs[mt].y;
          f32x4 xv;
          xv.x = __uint_as_float(w0 << 16);
          xv.y = __uint_as_float(w0 & 0xFFFF0000u);
          xv.z = __uint_as_float(w1 << 16);
          xv.w = __uint_as_float(w1 & 0xFFFF0000u);
          f32x4 ww = g[mt] * xv;            // row-scale by x (rows = src tags)
          p[mt][0] = cvt_pk_bf16(ww.x, ww.y);
          p[mt][1] = cvt_pk_bf16(ww.z, ww.w);
        }
        SWAPQ(p[0][0], p[1][0]); SWAPQ(p[0][1], p[1][1]);
        SWAPQ(p[2][0], p[3][0]); SWAPQ(p[2][1], p[3][1]);
        union { u32 u[4]; bf16x8 v; } B0, B1;
        B0.u[0] = p[0][0]; B0.u[1] = p[0][1]; B0.u[2] = p[1][0]; B0.u[3] = p[1][1];
        B1.u[0] = p[2][0]; B1.u[1] = p[2][1]; B1.u[2] = p[3][0]; B1.u[3] = p[3][1];

        const f32x4 zz = {0.f, 0.f, 0.f, 0.f};
#pragma unroll
        for (int mt = 0; mt < 4; ++mt) {    // hi-chain ∥ lo-chain
          f32x4 dh, dl;
          dh = __builtin_amdgcn_mfma_f32_16x16x32_bf16(eh[mt][0].v, B0.v, zz, 0, 0, 0);
          dh = __builtin_amdgcn_mfma_f32_16x16x32_bf16(eh[mt][1].v, B1.v, dh, 0, 0, 0);
          dl = __builtin_amdgcn_mfma_f32_16x16x32_bf16(el[mt][0].v, B0.v, zz, 0, 0, 0);
          dl = __builtin_amdgcn_mfma_f32_16x16x32_bf16(el[mt][1].v, B1.v, dl, 0, 0, 0);
          g[mt] = dh + dl;
        }
#pragma unroll
        for (int mt = 0; mt < 4; ++mt) xs[mt] = xn[mt];
      }
    }
#undef SWAPQ

    // ---- transpose via LDS, pack bf16, store row-major ----
#pragma unroll
    for (int mt = 0; mt < 4; ++mt)
#pragma unroll
      for (int r = 0; r < 4; ++r)
        sh.trs[(16 * mt + 4 * q + r) * 68 + 16 * w + c] = g[mt][r];
    __syncthreads();
    {
      int row = tid >> 2, qt = tid & 3;
      const float* src = sh.trs + row * 68 + qt * 16;
      u32 wp[8];
#pragma unroll
      for (int m = 0; m < 8; ++m) wp[m] = cvt_pk_bf16(src[2 * m], src[2 * m + 1]);
      u32x4* dst = (u32x4*)(Gout + (((size_t)(b * 8 + k) * 64 + row) * 64 + qt * 16));
      dst[0] = *(u32x4*)&wp[0];
      dst[1] = *(u32x4*)&wp[4];
    }
  }

  grid.sync();

  // ========================= phase 3: chain apply =========================
  if (blk < 64 && w == 0) {
    float* elds = sh.trs;            // 64 floats (wave-private, in-order DS)
    const int b = blk;
    const int j = l;
    const int L = seq[b];

    float A    = __expf(trans[j]);                                         // trans[BOS][j]
    float logZ = __logf(__uint_as_float((u32)xbuf[(size_t)b * NT] << 16)); // emit[0,b,BOS]

    const unsigned short* gbase = Gout + (size_t)b * 8 * 4096 + (size_t)j * 64;
    u32x4 gc[8], gn[8];
#pragma unroll
    for (int m = 0; m < 8; ++m) gc[m] = *((const u32x4*)gbase + m);

    const float C6 = 6.f * 0.6931471805599453f;

    for (int k = 0; k < 8; ++k) {
      if (k < 7) {
        const u32x4* gb2 = (const u32x4*)(gbase + (size_t)(k + 1) * 4096);
#pragma unroll
        for (int m = 0; m < 8; ++m) gn[m] = gb2[m];
      }
      int tb = 32 * k; if (tb < 1) tb = 1;
      int te = 32 * k + 32; if (te > L) te = L;
      int n = te - tb;
      if (n > 0) {
        elds[j] = A;
        float s0 = 0.f, s1 = 0.f, s2 = 0.f, s3 = 0.f;
#pragma unroll
        for (int m = 0; m < 8; ++m) {
          f32x4 av0 = *(const f32x4*)(elds + 8 * m);
          f32x4 av1 = *(const f32x4*)(elds + 8 * m + 4);
          u32x4 ww = gc[m];
          s0 = fmaf(av0.x, __uint_as_float(ww.x << 16),         s0);
          s1 = fmaf(av0.y, __uint_as_float(ww.x & 0xFFFF0000u), s1);
          s2 = fmaf(av0.z, __uint_as_float(ww.y << 16),         s2);
          s3 = fmaf(av0.w, __uint_as_float(ww.y & 0xFFFF0000u), s3);
          s0 = fmaf(av1.x, __uint_as_float(ww.z << 16),         s0);
          s1 = fmaf(av1.y, __uint_as_float(ww.z & 0xFFFF0000u), s1);
          s2 = fmaf(av1.z, __uint_as_float(ww.w << 16),         s2);
          s3 = fmaf(av1.w, __uint_as_float(ww.w & 0xFFFF0000u), s3);
        }
        A = (s0 + s1) + (s2 + s3);
        logZ += C6 * (float)n;
        u32 bb = __builtin_amdgcn_readfirstlane(__float_as_uint(A));
        int ex = (int)((bb >> 23) & 255u) - 127;
        A *= __uint_as_float((u32)(127 - ex) << 23);
        logZ += (float)ex * 0.6931471805599453f;
      }
      if (k < 7) {
#pragma unroll
        for (int m = 0; m < 8; ++m) gc[m] = gn[m];
      }
    }

    float res = logZ + __logf(A);
    res = __shfl(res, 1, 64);        // EOS = 1
    if (j == 0) atomicAdd(out, res);
  }
}

extern "C" void kernel_launch(void* const* d_in, const int* in_sizes, int n_in,
                              void* d_out, int out_size, void* d_ws, size_t ws_size,
                              hipStream_t stream) {
  const float* F     = (const float*)d_in[0];   // features (S,B,D) f32
  const int*   tags  = (const int*)  d_in[1];   // (S,B) i32
  const int*   seq   = (const int*)  d_in[2];   // (B,) i32
  const float* W     = (const float*)d_in[3];   // (T,D) f32
  const float* bias  = (const float*)d_in[4];   // (T,) f32
  const float* trans = (const float*)d_in[5];   // (T,T) f32
  float* out = (float*)d_out;

  char* ws = (char*)d_ws;
  // xbuf : 272 rows x 4096 bf16 (256 used + prefetch slack) @ 0        (2,228,224 B)
  // Wb3  : 128 KiB                                          @ 2228224
  // Ebuf : 16 KiB                                           @ 2359296
  // Gout : 64b x 8k x 64 x 64 bf16 = 4 MiB                  @ 2375680  (ends 6,569,984)
  unsigned short* xbuf = (unsigned short*)ws;
  unsigned short* Wb3  = (unsigned short*)(ws + 2228224);
  u32*            Ebuf = (u32*)(ws + 2359296);
  unsigned short* Gout = (unsigned short*)(ws + 2375680);

  void* args[] = { (void*)&F, (void*)&tags, (void*)&seq, (void*)&W, (void*)&bias,
                   (void*)&trans, (void*)&xbuf, (void*)&Wb3, (void*)&Ebuf,
                   (void*)&Gout, (void*)&out };
  hipLaunchCooperativeKernel((const void*)mega, dim3(512), dim3(256), args, 0, stream);
}

// Round 7
// 50.231 us; speedup vs baseline: 4.4484x; 4.4484x over previous
//
#include <hip/hip_runtime.h>

// Problem constants (fixed by reference): S=256, B=64, D=1024, T=64
#define SLEN 256
#define NB   64
#define ND   1024
#define NT   64
// BOS=0, EOS=1, PAD=2

typedef float f32x4  __attribute__((ext_vector_type(4)));
typedef short bf16x8 __attribute__((ext_vector_type(8)));
typedef __fp16 f16x8 __attribute__((ext_vector_type(8)));
typedef __fp16 f16x2 __attribute__((ext_vector_type(2)));
typedef unsigned int u32;
typedef u32 u32x2 __attribute__((ext_vector_type(2)));
typedef u32 u32x4 __attribute__((ext_vector_type(4)));
typedef int  i32x4 __attribute__((ext_vector_type(4)));

__device__ __forceinline__ u32 cvt_pk_bf16(float lo, float hi) {
  u32 r;
  asm("v_cvt_pk_bf16_f32 %0, %1, %2" : "=v"(r) : "v"(lo), "v"(hi));
  return r;
}

__device__ __forceinline__ u32 cvt_pk_f16(float lo, float hi) {
  union { f16x2 h; u32 u; } c;
  c.h = __builtin_amdgcn_cvt_pkrtz(lo, hi);   // returns __fp16 ext_vector(2)
  return c.u;
}

__device__ __forceinline__ unsigned short f2bf(float f) {   // RNE
  u32 u = __float_as_uint(f);
  return (unsigned short)((u + 0x7FFFu + ((u >> 16) & 1u)) >> 16);
}

__device__ __forceinline__ bf16x8 pack_bf16x8(f32x4 a, f32x4 b) {
  union { u32 u[4]; bf16x8 v; } r;
  r.u[0] = cvt_pk_bf16(a.x, a.y);
  r.u[1] = cvt_pk_bf16(a.z, a.w);
  r.u[2] = cvt_pk_bf16(b.x, b.y);
  r.u[3] = cvt_pk_bf16(b.z, b.w);
  return r.v;
}

__device__ __forceinline__ f32x4 vmax4(f32x4 a, f32x4 b) {
  f32x4 r;
  r.x = fmaxf(a.x, b.x); r.y = fmaxf(a.y, b.y);
  r.z = fmaxf(a.z, b.z); r.w = fmaxf(a.w, b.w);
  return r;
}

// ---------------------------------------------------------------------------
// Kernel 0: blocks 0..255: W -> bf16 frag-stream (B-frag of 16x16x32).
//           block 256:     fp16 E'^T A-frag table (8 KB) + zero out[0].
//   E-frag elem e, lane l=(q,c), tile (mt,kf):
//     fp16( exp(trans[(32kf+8q+e)*64 + 16mt+c]) * 2^-6 )
//   word layout: Ebuf[(mt*2+kf)*256 + l*4 + wd] = pkrtz(elem 2wd, elem 2wd+1)
// ---------------------------------------------------------------------------
__global__ __launch_bounds__(256) void prep(const float* __restrict__ W,
                                            const float* __restrict__ trans,
                                            unsigned short* __restrict__ Wb3,
                                            u32* __restrict__ Ebuf,
                                            float* __restrict__ out) {
  if (blockIdx.x < 256) {
    int o  = blockIdx.x * 256 + threadIdx.x;          // 0..65535
    int e  = o & 7;
    int l  = (o >> 3) & 63;
    int f  = (o >> 9) & 3;
    int k0 = o >> 11;
    int t  = f * 16 + (l & 15);
    int k  = k0 * 32 + ((l >> 4) << 3) + e;
    Wb3[o] = f2bf(W[t * ND + k]);
    return;
  }
  const int tid = threadIdx.x;
  if (tid == 0) out[0] = 0.f;
  const int l = tid & 63, wd = tid >> 6;              // wd = word 0..3
  const int q = l >> 4, c = l & 15;
#pragma unroll
  for (int mt = 0; mt < 4; ++mt)
#pragma unroll
    for (int kf = 0; kf < 2; ++kf) {
      float v0 = __expf(trans[(32 * kf + 8 * q + 2 * wd)     * NT + 16 * mt + c]) * 0.015625f;
      float v1 = __expf(trans[(32 * kf + 8 * q + 2 * wd + 1) * NT + 16 * mt + c]) * 0.015625f;
      Ebuf[(mt * 2 + kf) * 256 + l * 4 + wd] = cvt_pk_f16(v0, v1);
    }
}

// ---------------------------------------------------------------------------
// Kernel 1: xbuf[r][t] = bf16( exp( features[r]·W[t] + b[t] ) ), r = s*B+b.
// (R4-proven)
// ---------------------------------------------------------------------------
__global__ __launch_bounds__(256) void emit_gemm(const float* __restrict__ F,
                                                 const unsigned short* __restrict__ Wb3,
                                                 const float* __restrict__ bias,
                                                 unsigned short* __restrict__ xbuf) {
  const int lane = threadIdx.x & 63;
  const int wv   = (blockIdx.x * 256 + threadIdx.x) >> 6;  // 0..1023
  const int r0   = wv * 16;
  const int m    = lane & 15;
  const int kg   = lane >> 4;
  const float* arow = F + (size_t)(r0 + m) * ND + kg * 8;
  const bf16x8* bptr = reinterpret_cast<const bf16x8*>(Wb3) + lane;

  f32x4 acc0 = {0.f, 0.f, 0.f, 0.f};
  f32x4 acc1 = acc0, acc2 = acc0, acc3 = acc0;

  for (int g = 0; g < 32; g += 4) {
    f32x4  a[4][2];
    bf16x8 bb[4][4];
#pragma unroll
    for (int qq = 0; qq < 4; ++qq) {
      a[qq][0] = *(const f32x4*)(arow + (g + qq) * 32);
      a[qq][1] = *(const f32x4*)(arow + (g + qq) * 32 + 4);
#pragma unroll
      for (int f = 0; f < 4; ++f) bb[qq][f] = bptr[((g + qq) * 4 + f) * 64];
    }
#pragma unroll
    for (int qq = 0; qq < 4; ++qq) {
      bf16x8 af = pack_bf16x8(a[qq][0], a[qq][1]);
      acc0 = __builtin_amdgcn_mfma_f32_16x16x32_bf16(af, bb[qq][0], acc0, 0, 0, 0);
      acc1 = __builtin_amdgcn_mfma_f32_16x16x32_bf16(af, bb[qq][1], acc1, 0, 0, 0);
      acc2 = __builtin_amdgcn_mfma_f32_16x16x32_bf16(af, bb[qq][2], acc2, 0, 0, 0);
      acc3 = __builtin_amdgcn_mfma_f32_16x16x32_bf16(af, bb[qq][3], acc3, 0, 0, 0);
    }
  }

  const float bv0 = bias[m], bv1 = bias[16 + m], bv2 = bias[32 + m], bv3 = bias[48 + m];
  unsigned short* op = xbuf + (size_t)(r0 + kg * 4) * NT + m;
#pragma unroll
  for (int r = 0; r < 4; ++r) {
    op[r * NT +  0] = f2bf(__expf(acc0[r] + bv0));
    op[r * NT + 16] = f2bf(__expf(acc1[r] + bv1));
    op[r * NT + 32] = f2bf(__expf(acc2[r] + bv2));
    op[r * NT + 48] = f2bf(__expf(acc3[r] + bv3));
  }
}

// ---------------------------------------------------------------------------
// Kernel 2: per-(batch,chunk) product matrix, 32 steps, fp16 MFMA (8/step).
//   G <- E'^T · (x ⊙_rows G), E' = fp16(exp(trans)·2^-6) resident (32 VGPRs).
//   Per-wave (16-col group) power-of-2 renorm every 8 steps -> Gscale.
//   Wave 0 adds the chunk's gold-score slice. Output Gout bf16 row-major.
// ---------------------------------------------------------------------------
__global__ __launch_bounds__(256, 2) void chunk_prod(
    const unsigned short* __restrict__ xbuf, const float* __restrict__ trans,
    const u32* __restrict__ Ebuf, const int* __restrict__ tags,
    const int* __restrict__ seq_lens, unsigned short* __restrict__ Gout,
    int* __restrict__ Gscale, float* __restrict__ out) {
  __shared__ float trs[64 * 68];
  const int b   = blockIdx.x >> 3;
  const int k   = blockIdx.x & 7;
  const int tid = threadIdx.x;
  const int wid = tid >> 6;           // wave id = 16-column tile
  const int l   = tid & 63;
  const int q   = l >> 4, c = l & 15;

  const int L = seq_lens[b];          // in [2,256]

  // ---- gold slice: s in [32k, 32k+32) ∩ [0,L), wave 0 lanes 0..31 ----
  if (wid == 0) {
    float gp = 0.f;
    int s = 32 * k + (l & 31);
    if (l < 32 && s < L) {
      int tg = tags[s * NB + b];
      int nx = (s + 1 < SLEN) ? tags[(s + 1) * NB + b] : 2;
      float xv = __uint_as_float((u32)xbuf[(size_t)(s * NB + b) * NT + tg] << 16);
      gp = __logf(xv) + trans[tg * NT + nx];
    }
    gp += __shfl_xor(gp, 1, 64);
    gp += __shfl_xor(gp, 2, 64);
    gp += __shfl_xor(gp, 4, 64);
    gp += __shfl_xor(gp, 8, 64);
    gp += __shfl_xor(gp, 16, 64);
    if (l == 0) atomicAdd(out, -gp);
  }

  // ---- resident fp16 E'^T A-frags (32 VGPRs) ----
  union uf { u32x4 u; f16x8 v; };
  uf ef[4][2];
#pragma unroll
  for (int mt = 0; mt < 4; ++mt)
#pragma unroll
    for (int kf = 0; kf < 2; ++kf)
      ef[mt][kf].u = *(const u32x4*)(Ebuf + (mt * 2 + kf) * 256 + l * 4);

  // ---- G = I (this wave's 16-column tile): G[16mt+4q+r][16wid+c] ----
  f32x4 g0 = {0,0,0,0}, g1 = g0, g2 = g0, g3 = g0;
  {
    int r = c - 4 * q;
    if (r >= 0 && r < 4) {
      float one = 1.0f;
      if (wid == 0) g0[r & 3] = one;
      else if (wid == 1) g1[r & 3] = one;
      else if (wid == 2) g2[r & 3] = one;
      else g3[r & 3] = one;
    }
  }

  int tbeg = 32 * k; if (tbeg < 1) tbeg = 1;
  int tend = 32 * k + 32; if (tend > L) tend = L;
  int exw = 0;

  const unsigned short* xb = xbuf + (size_t)b * NT + 4 * q;

#define SWAPQ(A, B) do {                                                  \
    asm("v_permlane32_swap_b32 %0, %1" : "+v"(A), "+v"(B));               \
    asm("v_permlane16_swap_b32 %0, %1" : "+v"(A), "+v"(B));               \
  } while (0)

#define LOADX(X, T) do {                                                  \
    X[0] = *(const u32x2*)(xb + (size_t)(T) * (NB * NT));                 \
    X[1] = *(const u32x2*)(xb + (size_t)(T) * (NB * NT) + 16);            \
    X[2] = *(const u32x2*)(xb + (size_t)(T) * (NB * NT) + 32);            \
    X[3] = *(const u32x2*)(xb + (size_t)(T) * (NB * NT) + 48);            \
  } while (0)

#define MULPK(P0, P1, G, XW) do {                                         \
    f32x4 xv;                                                             \
    xv.x = __uint_as_float(XW.x << 16);                                   \
    xv.y = __uint_as_float(XW.x & 0xFFFF0000u);                           \
    xv.z = __uint_as_float(XW.y << 16);                                   \
    xv.w = __uint_as_float(XW.y & 0xFFFF0000u);                           \
    f32x4 ww = G * xv;                                                    \
    P0 = cvt_pk_f16(ww.x, ww.y);                                          \
    P1 = cvt_pk_f16(ww.z, ww.w);                                          \
  } while (0)

#define STEPF(X, T) do {                                                  \
    if ((((T) & 7) == 0) && ((T) != tbeg)) {     /* per-wave renorm */    \
      f32x4 m4 = vmax4(vmax4(g0, g1), vmax4(g2, g3));                     \
      float mx = fmaxf(fmaxf(m4.x, m4.y), fmaxf(m4.z, m4.w));             \
      mx = fmaxf(mx, __shfl_xor(mx, 1, 64));                              \
      mx = fmaxf(mx, __shfl_xor(mx, 2, 64));                              \
      mx = fmaxf(mx, __shfl_xor(mx, 4, 64));                              \
      mx = fmaxf(mx, __shfl_xor(mx, 8, 64));                              \
      mx = fmaxf(mx, __shfl_xor(mx, 16, 64));                             \
      mx = fmaxf(mx, __shfl_xor(mx, 32, 64));                             \
      int ex = (int)((__float_as_uint(mx) >> 23) & 255u) - 127;           \
      float sc = __uint_as_float((u32)(127 - ex) << 23);                  \
      g0 *= sc; g1 *= sc; g2 *= sc; g3 *= sc; exw += ex;                  \
    }                                                                     \
    u32 p00, p01, p10, p11, p20, p21, p30, p31;                           \
    MULPK(p00, p01, g0, X[0]);                                            \
    MULPK(p10, p11, g1, X[1]);                                            \
    MULPK(p20, p21, g2, X[2]);                                            \
    MULPK(p30, p31, g3, X[3]);                                            \
    SWAPQ(p00, p10); SWAPQ(p01, p11); SWAPQ(p20, p30); SWAPQ(p21, p31);   \
    uf B0, B1;                                                            \
    B0.u[0] = p00; B0.u[1] = p01; B0.u[2] = p10; B0.u[3] = p11;           \
    B1.u[0] = p20; B1.u[1] = p21; B1.u[2] = p30; B1.u[3] = p31;           \
    const f32x4 zz = {0.f, 0.f, 0.f, 0.f};                                \
    g0 = __builtin_amdgcn_mfma_f32_16x16x32_f16(ef[0][0].v, B0.v, zz, 0, 0, 0); \
    g0 = __builtin_amdgcn_mfma_f32_16x16x32_f16(ef[0][1].v, B1.v, g0, 0, 0, 0); \
    g1 = __builtin_amdgcn_mfma_f32_16x16x32_f16(ef[1][0].v, B0.v, zz, 0, 0, 0); \
    g1 = __builtin_amdgcn_mfma_f32_16x16x32_f16(ef[1][1].v, B1.v, g1, 0, 0, 0); \
    g2 = __builtin_amdgcn_mfma_f32_16x16x32_f16(ef[2][0].v, B0.v, zz, 0, 0, 0); \
    g2 = __builtin_amdgcn_mfma_f32_16x16x32_f16(ef[2][1].v, B1.v, g2, 0, 0, 0); \
    g3 = __builtin_amdgcn_mfma_f32_16x16x32_f16(ef[3][0].v, B0.v, zz, 0, 0, 0); \
    g3 = __builtin_amdgcn_mfma_f32_16x16x32_f16(ef[3][1].v, B1.v, g3, 0, 0, 0); \
  } while (0)

  if (tbeg < tend) {
    u32x2 XA[4], XB[4];
    int t = tbeg;
    LOADX(XA, t);
    for (; t + 1 < tend; t += 2) {
      LOADX(XB, t + 1);
      STEPF(XA, t);
      LOADX(XA, t + 2);      // row <= tend <= 256 (slack rows exist)
      STEPF(XB, t + 1);
    }
    if (t < tend) STEPF(XA, t);
  }
#undef STEPF
#undef MULPK
#undef LOADX
#undef SWAPQ

  if (l == 0) Gscale[((size_t)b * 8 + k) * 4 + wid] = exw;

  // ---- transpose via LDS, pack bf16, store row-major ----
#pragma unroll
  for (int r = 0; r < 4; ++r) {
    trs[(4 * q + r) * 68      + 16 * wid + c] = g0[r];
    trs[(16 + 4 * q + r) * 68 + 16 * wid + c] = g1[r];
    trs[(32 + 4 * q + r) * 68 + 16 * wid + c] = g2[r];
    trs[(48 + 4 * q + r) * 68 + 16 * wid + c] = g3[r];
  }
  __syncthreads();
  {
    int row = tid >> 2, qt = tid & 3;
    const float* src = trs + row * 68 + qt * 16;
    u32 wp[8];
#pragma unroll
    for (int m = 0; m < 8; ++m) wp[m] = cvt_pk_bf16(src[2 * m], src[2 * m + 1]);
    u32x4* dst = (u32x4*)(Gout + (((size_t)(b * 8 + k) * 64 + row) * 64 + qt * 16));
    dst[0] = *(u32x4*)&wp[0];
    dst[1] = *(u32x4*)&wp[4];
  }
}

// ---------------------------------------------------------------------------
// Kernel 3: per-batch alpha scan through 8 chunk matrices with per-column-
// group 2^e scales; atomicAdd the batch's logZ contribution into out.
// ---------------------------------------------------------------------------
__global__ __launch_bounds__(64, 1) void chain_apply(
    const unsigned short* __restrict__ xbuf, const float* __restrict__ trans,
    const unsigned short* __restrict__ Gout, const int* __restrict__ Gscale,
    const int* __restrict__ seq_lens, float* __restrict__ out) {
  __shared__ __align__(16) float elds[64];
  const int b = blockIdx.x;
  const int j = threadIdx.x;
  const int L = seq_lens[b];

  float A    = __expf(trans[j]);                                         // trans[BOS][j]
  float logZ = __logf(__uint_as_float((u32)xbuf[(size_t)b * NT] << 16)); // emit[0,b,BOS]

  const unsigned short* gbase = Gout + (size_t)b * 8 * 4096 + (size_t)j * 64;
  const i32x4* sbase = (const i32x4*)(Gscale + (size_t)b * 8 * 4);
  u32x4 gc[8], gn[8];
  i32x4 scc, scn;
#pragma unroll
  for (int m = 0; m < 8; ++m) gc[m] = *((const u32x4*)gbase + m);
  scc = sbase[0];

  const float C6 = 6.f * 0.6931471805599453f;

  for (int k = 0; k < 8; ++k) {
    if (k < 7) {
      const u32x4* gb2 = (const u32x4*)(gbase + (size_t)(k + 1) * 4096);
#pragma unroll
      for (int m = 0; m < 8; ++m) gn[m] = gb2[m];
      scn = sbase[k + 1];
    }
    int tb = 32 * k; if (tb < 1) tb = 1;
    int te = 32 * k + 32; if (te > L) te = L;
    int n = te - tb;
    if (n > 0) {
      elds[j] = A;                    // same-wave DS ordering (R1-proven)
      float sA0 = 0.f, sA1 = 0.f, sA2 = 0.f, sA3 = 0.f;
      float sB0 = 0.f, sB1 = 0.f, sB2 = 0.f, sB3 = 0.f;
#pragma unroll
      for (int m = 0; m < 8; ++m) {
        f32x4 av0 = *(const f32x4*)(elds + 8 * m);
        f32x4 av1 = *(const f32x4*)(elds + 8 * m + 4);
        u32x4 w = gc[m];
        float a0, a1;
        a0 = fmaf(av0.x, __uint_as_float(w.x << 16),         0.f);
        a0 = fmaf(av0.y, __uint_as_float(w.x & 0xFFFF0000u), a0);
        a0 = fmaf(av0.z, __uint_as_float(w.y << 16),         a0);
        a0 = fmaf(av0.w, __uint_as_float(w.y & 0xFFFF0000u), a0);
        a1 = fmaf(av1.x, __uint_as_float(w.z << 16),         0.f);
        a1 = fmaf(av1.y, __uint_as_float(w.z & 0xFFFF0000u), a1);
        a1 = fmaf(av1.z, __uint_as_float(w.w << 16),         a1);
        a1 = fmaf(av1.w, __uint_as_float(w.w & 0xFFFF0000u), a1);
        switch (m >> 1) {
          case 0: if (m & 1) { sB0 += a0 + a1; } else { sA0 += a0 + a1; } break;
          case 1: if (m & 1) { sB1 += a0 + a1; } else { sA1 += a0 + a1; } break;
          case 2: if (m & 1) { sB2 += a0 + a1; } else { sA2 += a0 + a1; } break;
          default: if (m & 1) { sB3 += a0 + a1; } else { sA3 += a0 + a1; } break;
        }
      }
      float sc0 = __uint_as_float((u32)(127 + scc.x) << 23);
      float sc1 = __uint_as_float((u32)(127 + scc.y) << 23);
      float sc2 = __uint_as_float((u32)(127 + scc.z) << 23);
      float sc3 = __uint_as_float((u32)(127 + scc.w) << 23);
      A = ((sA0 + sB0) * sc0 + (sA1 + sB1) * sc1)
        + ((sA2 + sB2) * sc2 + (sA3 + sB3) * sc3);
      logZ += C6 * (float)n;
      u32 bb = __builtin_amdgcn_readfirstlane(__float_as_uint(A));
      int ex = (int)((bb >> 23) & 255u) - 127;
      A *= __uint_as_float((u32)(127 - ex) << 23);
      logZ += (float)ex * 0.6931471805599453f;
    }
    if (k < 7) {
#pragma unroll
      for (int m = 0; m < 8; ++m) gc[m] = gn[m];
      scc = scn;
    }
  }

  float res = logZ + __logf(A);
  res = __shfl(res, 1, 64);           // EOS = 1
  if (j == 0) atomicAdd(out, res);
}

extern "C" void kernel_launch(void* const* d_in, const int* in_sizes, int n_in,
                              void* d_out, int out_size, void* d_ws, size_t ws_size,
                              hipStream_t stream) {
  const float* F     = (const float*)d_in[0];   // features (S,B,D) f32
  const int*   tags  = (const int*)  d_in[1];   // (S,B) i32
  const int*   seq   = (const int*)  d_in[2];   // (B,) i32
  const float* W     = (const float*)d_in[3];   // (T,D) f32
  const float* bias  = (const float*)d_in[4];   // (T,) f32
  const float* trans = (const float*)d_in[5];   // (T,T) f32
  float* out = (float*)d_out;

  char* ws = (char*)d_ws;
  // xbuf  : 272 rows x 4096 bf16 (256 used + slack)  @ 0        (2,228,224 B)
  // Wb3   : 128 KiB                                  @ 2228224
  // Ebuf  : 8 KiB (fp16 E table)                     @ 2359296
  // Gout  : 64b x 8k x 64 x 64 bf16 = 4 MiB          @ 2367488
  // Gscale: 64 x 8 x 4 i32 = 8 KiB                   @ 6561792  (ends 6,569,984)
  unsigned short* xbuf   = (unsigned short*)ws;
  unsigned short* Wb3    = (unsigned short*)(ws + 2228224);
  u32*            Ebuf   = (u32*)(ws + 2359296);
  unsigned short* Gout   = (unsigned short*)(ws + 2367488);
  int*            Gscale = (int*)(ws + 6561792);

  prep       <<<257, 256, 0, stream>>>(W, trans, Wb3, Ebuf, out);
  emit_gemm  <<<256, 256, 0, stream>>>(F, Wb3, bias, xbuf);
  chunk_prod <<<512, 256, 0, stream>>>(xbuf, trans, Ebuf, tags, seq, Gout, Gscale, out);
  chain_apply<<<64,   64, 0, stream>>>(xbuf, trans, Gout, Gscale, seq, out);
}

// Round 8
// 44.774 us; speedup vs baseline: 4.9906x; 1.1219x over previous
//
#include <hip/hip_runtime.h>

// Problem constants (fixed by reference): S=256, B=64, D=1024, T=64
#define SLEN 256
#define NB   64
#define ND   1024
#define NT   64
// BOS=0, EOS=1, PAD=2

typedef float f32x4  __attribute__((ext_vector_type(4)));
typedef short bf16x8 __attribute__((ext_vector_type(8)));
typedef __fp16 f16x8 __attribute__((ext_vector_type(8)));
typedef __fp16 f16x2 __attribute__((ext_vector_type(2)));
typedef unsigned int u32;
typedef u32 u32x2 __attribute__((ext_vector_type(2)));
typedef u32 u32x4 __attribute__((ext_vector_type(4)));
typedef int  i32x4 __attribute__((ext_vector_type(4)));

__device__ __forceinline__ u32 cvt_pk_bf16(float lo, float hi) {
  u32 r;
  asm("v_cvt_pk_bf16_f32 %0, %1, %2" : "=v"(r) : "v"(lo), "v"(hi));
  return r;
}

__device__ __forceinline__ u32 cvt_pk_f16(float lo, float hi) {
  union { f16x2 h; u32 u; } c;
  c.h = __builtin_amdgcn_cvt_pkrtz(lo, hi);   // returns __fp16 ext_vector(2)
  return c.u;
}

__device__ __forceinline__ unsigned short f2bf(float f) {   // RNE
  u32 u = __float_as_uint(f);
  return (unsigned short)((u + 0x7FFFu + ((u >> 16) & 1u)) >> 16);
}

__device__ __forceinline__ bf16x8 pack_bf16x8(f32x4 a, f32x4 b) {
  union { u32 u[4]; bf16x8 v; } r;
  r.u[0] = cvt_pk_bf16(a.x, a.y);
  r.u[1] = cvt_pk_bf16(a.z, a.w);
  r.u[2] = cvt_pk_bf16(b.x, b.y);
  r.u[3] = cvt_pk_bf16(b.z, b.w);
  return r.v;
}

__device__ __forceinline__ f32x4 vmax4(f32x4 a, f32x4 b) {
  f32x4 r;
  r.x = fmaxf(a.x, b.x); r.y = fmaxf(a.y, b.y);
  r.z = fmaxf(a.z, b.z); r.w = fmaxf(a.w, b.w);
  return r;
}

// ---------------------------------------------------------------------------
// Kernel 0: blocks 0..255: W -> bf16 frag-stream (B-frag of 16x16x32).
//           block 256:     fp16 E'^T A-frag table (8 KB) + zero out[0].
// (R7-proven)
// ---------------------------------------------------------------------------
__global__ __launch_bounds__(256) void prep(const float* __restrict__ W,
                                            const float* __restrict__ trans,
                                            unsigned short* __restrict__ Wb3,
                                            u32* __restrict__ Ebuf,
                                            float* __restrict__ out) {
  if (blockIdx.x < 256) {
    int o  = blockIdx.x * 256 + threadIdx.x;          // 0..65535
    int e  = o & 7;
    int l  = (o >> 3) & 63;
    int f  = (o >> 9) & 3;
    int k0 = o >> 11;
    int t  = f * 16 + (l & 15);
    int k  = k0 * 32 + ((l >> 4) << 3) + e;
    Wb3[o] = f2bf(W[t * ND + k]);
    return;
  }
  const int tid = threadIdx.x;
  if (tid == 0) out[0] = 0.f;
  const int l = tid & 63, wd = tid >> 6;              // wd = word 0..3
  const int q = l >> 4, c = l & 15;
#pragma unroll
  for (int mt = 0; mt < 4; ++mt)
#pragma unroll
    for (int kf = 0; kf < 2; ++kf) {
      float v0 = __expf(trans[(32 * kf + 8 * q + 2 * wd)     * NT + 16 * mt + c]) * 0.015625f;
      float v1 = __expf(trans[(32 * kf + 8 * q + 2 * wd + 1) * NT + 16 * mt + c]) * 0.015625f;
      Ebuf[(mt * 2 + kf) * 256 + l * 4 + wd] = cvt_pk_f16(v0, v1);
    }
}

// ---------------------------------------------------------------------------
// Kernel 1: xbuf[r][t] = bf16( exp( features[r]·W[t] + b[t] ) ), r = s*B+b.
// (R4-proven)
// ---------------------------------------------------------------------------
__global__ __launch_bounds__(256) void emit_gemm(const float* __restrict__ F,
                                                 const unsigned short* __restrict__ Wb3,
                                                 const float* __restrict__ bias,
                                                 unsigned short* __restrict__ xbuf) {
  const int lane = threadIdx.x & 63;
  const int wv   = (blockIdx.x * 256 + threadIdx.x) >> 6;  // 0..1023
  const int r0   = wv * 16;
  const int m    = lane & 15;
  const int kg   = lane >> 4;
  const float* arow = F + (size_t)(r0 + m) * ND + kg * 8;
  const bf16x8* bptr = reinterpret_cast<const bf16x8*>(Wb3) + lane;

  f32x4 acc0 = {0.f, 0.f, 0.f, 0.f};
  f32x4 acc1 = acc0, acc2 = acc0, acc3 = acc0;

  for (int g = 0; g < 32; g += 4) {
    f32x4  a[4][2];
    bf16x8 bb[4][4];
#pragma unroll
    for (int qq = 0; qq < 4; ++qq) {
      a[qq][0] = *(const f32x4*)(arow + (g + qq) * 32);
      a[qq][1] = *(const f32x4*)(arow + (g + qq) * 32 + 4);
#pragma unroll
      for (int f = 0; f < 4; ++f) bb[qq][f] = bptr[((g + qq) * 4 + f) * 64];
    }
#pragma unroll
    for (int qq = 0; qq < 4; ++qq) {
      bf16x8 af = pack_bf16x8(a[qq][0], a[qq][1]);
      acc0 = __builtin_amdgcn_mfma_f32_16x16x32_bf16(af, bb[qq][0], acc0, 0, 0, 0);
      acc1 = __builtin_amdgcn_mfma_f32_16x16x32_bf16(af, bb[qq][1], acc1, 0, 0, 0);
      acc2 = __builtin_amdgcn_mfma_f32_16x16x32_bf16(af, bb[qq][2], acc2, 0, 0, 0);
      acc3 = __builtin_amdgcn_mfma_f32_16x16x32_bf16(af, bb[qq][3], acc3, 0, 0, 0);
    }
  }

  const float bv0 = bias[m], bv1 = bias[16 + m], bv2 = bias[32 + m], bv3 = bias[48 + m];
  unsigned short* op = xbuf + (size_t)(r0 + kg * 4) * NT + m;
#pragma unroll
  for (int r = 0; r < 4; ++r) {
    op[r * NT +  0] = f2bf(__expf(acc0[r] + bv0));
    op[r * NT + 16] = f2bf(__expf(acc1[r] + bv1));
    op[r * NT + 32] = f2bf(__expf(acc2[r] + bv2));
    op[r * NT + 48] = f2bf(__expf(acc3[r] + bv3));
  }
}

// ---------------------------------------------------------------------------
// Kernel 2: per-(batch,chunk) product matrix, 32 steps, fp16 MFMA (8/step).
// R8 changes vs R7: (a) chunk's x (4 KB) staged to LDS once -> zero vmem in
// the step loop (reads are 16-lane-uniform ds_read_b64 broadcasts);
// (b) gold partial WRITTEN to Gpart[b][k] instead of 512-way same-address
// atomicAdd (cross-XCD contention suspect).
// ---------------------------------------------------------------------------
__global__ __launch_bounds__(256, 2) void chunk_prod(
    const unsigned short* __restrict__ xbuf, const float* __restrict__ trans,
    const u32* __restrict__ Ebuf, const int* __restrict__ tags,
    const int* __restrict__ seq_lens, unsigned short* __restrict__ Gout,
    int* __restrict__ Gscale, float* __restrict__ Gpart) {
  __shared__ float trs[64 * 68];
  __shared__ unsigned short xlds[34 * 64];   // 32 rows used + slack for prefetch
  const int b   = blockIdx.x >> 3;
  const int k   = blockIdx.x & 7;
  const int tid = threadIdx.x;
  const int wid = tid >> 6;           // wave id = 16-column tile
  const int l   = tid & 63;
  const int q   = l >> 4, c = l & 15;

  const int L = seq_lens[b];          // in [2,256]

  // ---- stage x-chunk to LDS: rows t = 32k .. 32k+31 of batch b (4 KB) ----
  {
    int tp  = tid >> 3;               // 0..31
    int cg  = (tid & 7) * 8;          // 8 bf16 per thread
    const u32x4* s4 = (const u32x4*)(xbuf + ((size_t)((32 * k + tp) * NB + b)) * NT + cg);
    *(u32x4*)(xlds + tp * 64 + cg) = *s4;
  }

  // ---- gold slice: s in [32k, 32k+32) ∩ [0,L), wave 0 lanes 0..31 ----
  if (wid == 0) {
    float gp = 0.f;
    int s = 32 * k + (l & 31);
    if (l < 32 && s < L) {
      int tg = tags[s * NB + b];
      int nx = (s + 1 < SLEN) ? tags[(s + 1) * NB + b] : 2;
      float xv = __uint_as_float((u32)xbuf[(size_t)(s * NB + b) * NT + tg] << 16);
      gp = __logf(xv) + trans[tg * NT + nx];
    }
    gp += __shfl_xor(gp, 1, 64);
    gp += __shfl_xor(gp, 2, 64);
    gp += __shfl_xor(gp, 4, 64);
    gp += __shfl_xor(gp, 8, 64);
    gp += __shfl_xor(gp, 16, 64);
    if (l == 0) Gpart[b * 8 + k] = gp;
  }

  // ---- resident fp16 E'^T A-frags (32 VGPRs) ----
  union uf { u32x4 u; f16x8 v; };
  uf ef[4][2];
#pragma unroll
  for (int mt = 0; mt < 4; ++mt)
#pragma unroll
    for (int kf = 0; kf < 2; ++kf)
      ef[mt][kf].u = *(const u32x4*)(Ebuf + (mt * 2 + kf) * 256 + l * 4);

  // ---- G = I (this wave's 16-column tile): G[16mt+4q+r][16wid+c] ----
  f32x4 g0 = {0,0,0,0}, g1 = g0, g2 = g0, g3 = g0;
  {
    int r = c - 4 * q;
    if (r >= 0 && r < 4) {
      float one = 1.0f;
      if (wid == 0) g0[r & 3] = one;
      else if (wid == 1) g1[r & 3] = one;
      else if (wid == 2) g2[r & 3] = one;
      else g3[r & 3] = one;
    }
  }

  int tbeg = 32 * k; if (tbeg < 1) tbeg = 1;
  int tend = 32 * k + 32; if (tend > L) tend = L;
  int exw = 0;

  __syncthreads();                    // xlds ready

#define SWAPQ(A, B) do {                                                  \
    asm("v_permlane32_swap_b32 %0, %1" : "+v"(A), "+v"(B));               \
    asm("v_permlane16_swap_b32 %0, %1" : "+v"(A), "+v"(B));               \
  } while (0)

#define LOADX(X, TP) do {                                                 \
    X[0] = *(const u32x2*)(xlds + (TP) * 64 + 4 * q);                     \
    X[1] = *(const u32x2*)(xlds + (TP) * 64 + 16 + 4 * q);                \
    X[2] = *(const u32x2*)(xlds + (TP) * 64 + 32 + 4 * q);                \
    X[3] = *(const u32x2*)(xlds + (TP) * 64 + 48 + 4 * q);                \
  } while (0)

#define MULPK(P0, P1, G, XW) do {                                         \
    f32x4 xv;                                                             \
    xv.x = __uint_as_float(XW.x << 16);                                   \
    xv.y = __uint_as_float(XW.x & 0xFFFF0000u);                           \
    xv.z = __uint_as_float(XW.y << 16);                                   \
    xv.w = __uint_as_float(XW.y & 0xFFFF0000u);                           \
    f32x4 ww = G * xv;                                                    \
    P0 = cvt_pk_f16(ww.x, ww.y);                                          \
    P1 = cvt_pk_f16(ww.z, ww.w);                                          \
  } while (0)

#define STEPF(X, T) do {                                                  \
    if ((((T) & 7) == 0) && ((T) != tbeg)) {     /* per-wave renorm */    \
      f32x4 m4 = vmax4(vmax4(g0, g1), vmax4(g2, g3));                     \
      float mx = fmaxf(fmaxf(m4.x, m4.y), fmaxf(m4.z, m4.w));             \
      mx = fmaxf(mx, __shfl_xor(mx, 1, 64));                              \
      mx = fmaxf(mx, __shfl_xor(mx, 2, 64));                              \
      mx = fmaxf(mx, __shfl_xor(mx, 4, 64));                              \
      mx = fmaxf(mx, __shfl_xor(mx, 8, 64));                              \
      mx = fmaxf(mx, __shfl_xor(mx, 16, 64));                             \
      mx = fmaxf(mx, __shfl_xor(mx, 32, 64));                             \
      int ex = (int)((__float_as_uint(mx) >> 23) & 255u) - 127;           \
      float sc = __uint_as_float((u32)(127 - ex) << 23);                  \
      g0 *= sc; g1 *= sc; g2 *= sc; g3 *= sc; exw += ex;                  \
    }                                                                     \
    u32 p00, p01, p10, p11, p20, p21, p30, p31;                           \
    MULPK(p00, p01, g0, X[0]);                                            \
    MULPK(p10, p11, g1, X[1]);                                            \
    MULPK(p20, p21, g2, X[2]);                                            \
    MULPK(p30, p31, g3, X[3]);                                            \
    SWAPQ(p00, p10); SWAPQ(p01, p11); SWAPQ(p20, p30); SWAPQ(p21, p31);   \
    uf B0, B1;                                                            \
    B0.u[0] = p00; B0.u[1] = p01; B0.u[2] = p10; B0.u[3] = p11;           \
    B1.u[0] = p20; B1.u[1] = p21; B1.u[2] = p30; B1.u[3] = p31;           \
    const f32x4 zz = {0.f, 0.f, 0.f, 0.f};                                \
    g0 = __builtin_amdgcn_mfma_f32_16x16x32_f16(ef[0][0].v, B0.v, zz, 0, 0, 0); \
    g0 = __builtin_amdgcn_mfma_f32_16x16x32_f16(ef[0][1].v, B1.v, g0, 0, 0, 0); \
    g1 = __builtin_amdgcn_mfma_f32_16x16x32_f16(ef[1][0].v, B0.v, zz, 0, 0, 0); \
    g1 = __builtin_amdgcn_mfma_f32_16x16x32_f16(ef[1][1].v, B1.v, g1, 0, 0, 0); \
    g2 = __builtin_amdgcn_mfma_f32_16x16x32_f16(ef[2][0].v, B0.v, zz, 0, 0, 0); \
    g2 = __builtin_amdgcn_mfma_f32_16x16x32_f16(ef[2][1].v, B1.v, g2, 0, 0, 0); \
    g3 = __builtin_amdgcn_mfma_f32_16x16x32_f16(ef[3][0].v, B0.v, zz, 0, 0, 0); \
    g3 = __builtin_amdgcn_mfma_f32_16x16x32_f16(ef[3][1].v, B1.v, g3, 0, 0, 0); \
  } while (0)

  if (tbeg < tend) {
    u32x2 XA[4], XB[4];
    int tp  = tbeg - 32 * k;          // 0 or 1
    int tpe = tend - 32 * k;          // <= 32
    LOADX(XA, tp);
    for (; tp + 1 < tpe; tp += 2) {
      LOADX(XB, tp + 1);
      STEPF(XA, tp + 32 * k);
      LOADX(XA, tp + 2);              // row <= 33: xlds has slack
      STEPF(XB, tp + 1 + 32 * k);
    }
    if (tp < tpe) STEPF(XA, tp + 32 * k);
  }
#undef STEPF
#undef MULPK
#undef LOADX
#undef SWAPQ

  if (l == 0) Gscale[((size_t)b * 8 + k) * 4 + wid] = exw;

  // ---- transpose via LDS, pack bf16, store row-major ----
#pragma unroll
  for (int r = 0; r < 4; ++r) {
    trs[(4 * q + r) * 68      + 16 * wid + c] = g0[r];
    trs[(16 + 4 * q + r) * 68 + 16 * wid + c] = g1[r];
    trs[(32 + 4 * q + r) * 68 + 16 * wid + c] = g2[r];
    trs[(48 + 4 * q + r) * 68 + 16 * wid + c] = g3[r];
  }
  __syncthreads();
  {
    int row = tid >> 2, qt = tid & 3;
    const float* src = trs + row * 68 + qt * 16;
    u32 wp[8];
#pragma unroll
    for (int m = 0; m < 8; ++m) wp[m] = cvt_pk_bf16(src[2 * m], src[2 * m + 1]);
    u32x4* dst = (u32x4*)(Gout + (((size_t)(b * 8 + k) * 64 + row) * 64 + qt * 16));
    dst[0] = *(u32x4*)&wp[0];
    dst[1] = *(u32x4*)&wp[4];
  }
}

// ---------------------------------------------------------------------------
// Kernel 3: per-batch alpha scan through 8 chunk matrices with per-column-
// group 2^e scales; subtract the batch's gold partials (Gpart) and atomicAdd
// the batch's contribution into out (64 atomics total).
// ---------------------------------------------------------------------------
__global__ __launch_bounds__(64, 1) void chain_apply(
    const unsigned short* __restrict__ xbuf, const float* __restrict__ trans,
    const unsigned short* __restrict__ Gout, const int* __restrict__ Gscale,
    const float* __restrict__ Gpart, const int* __restrict__ seq_lens,
    float* __restrict__ out) {
  __shared__ __align__(16) float elds[64];
  const int b = blockIdx.x;
  const int j = threadIdx.x;
  const int L = seq_lens[b];

  // gold = sum of the 8 chunk partials
  float gp = (j < 8) ? Gpart[b * 8 + j] : 0.f;
  gp += __shfl_xor(gp, 1, 64);
  gp += __shfl_xor(gp, 2, 64);
  gp += __shfl_xor(gp, 4, 64);      // lanes 0..7 all hold the sum

  float A    = __expf(trans[j]);                                         // trans[BOS][j]
  float logZ = __logf(__uint_as_float((u32)xbuf[(size_t)b * NT] << 16)); // emit[0,b,BOS]

  const unsigned short* gbase = Gout + (size_t)b * 8 * 4096 + (size_t)j * 64;
  const i32x4* sbase = (const i32x4*)(Gscale + (size_t)b * 8 * 4);
  u32x4 gc[8], gn[8];
  i32x4 scc, scn;
#pragma unroll
  for (int m = 0; m < 8; ++m) gc[m] = *((const u32x4*)gbase + m);
  scc = sbase[0];

  const float C6 = 6.f * 0.6931471805599453f;

  for (int k = 0; k < 8; ++k) {
    if (k < 7) {
      const u32x4* gb2 = (const u32x4*)(gbase + (size_t)(k + 1) * 4096);
#pragma unroll
      for (int m = 0; m < 8; ++m) gn[m] = gb2[m];
      scn = sbase[k + 1];
    }
    int tb = 32 * k; if (tb < 1) tb = 1;
    int te = 32 * k + 32; if (te > L) te = L;
    int n = te - tb;
    if (n > 0) {
      elds[j] = A;                    // same-wave DS ordering (R1-proven)
      float sA0 = 0.f, sA1 = 0.f, sA2 = 0.f, sA3 = 0.f;
      float sB0 = 0.f, sB1 = 0.f, sB2 = 0.f, sB3 = 0.f;
#pragma unroll
      for (int m = 0; m < 8; ++m) {
        f32x4 av0 = *(const f32x4*)(elds + 8 * m);
        f32x4 av1 = *(const f32x4*)(elds + 8 * m + 4);
        u32x4 w = gc[m];
        float a0, a1;
        a0 = fmaf(av0.x, __uint_as_float(w.x << 16),         0.f);
        a0 = fmaf(av0.y, __uint_as_float(w.x & 0xFFFF0000u), a0);
        a0 = fmaf(av0.z, __uint_as_float(w.y << 16),         a0);
        a0 = fmaf(av0.w, __uint_as_float(w.y & 0xFFFF0000u), a0);
        a1 = fmaf(av1.x, __uint_as_float(w.z << 16),         0.f);
        a1 = fmaf(av1.y, __uint_as_float(w.z & 0xFFFF0000u), a1);
        a1 = fmaf(av1.z, __uint_as_float(w.w << 16),         a1);
        a1 = fmaf(av1.w, __uint_as_float(w.w & 0xFFFF0000u), a1);
        switch (m >> 1) {
          case 0: if (m & 1) { sB0 += a0 + a1; } else { sA0 += a0 + a1; } break;
          case 1: if (m & 1) { sB1 += a0 + a1; } else { sA1 += a0 + a1; } break;
          case 2: if (m & 1) { sB2 += a0 + a1; } else { sA2 += a0 + a1; } break;
          default: if (m & 1) { sB3 += a0 + a1; } else { sA3 += a0 + a1; } break;
        }
      }
      float sc0 = __uint_as_float((u32)(127 + scc.x) << 23);
      float sc1 = __uint_as_float((u32)(127 + scc.y) << 23);
      float sc2 = __uint_as_float((u32)(127 + scc.z) << 23);
      float sc3 = __uint_as_float((u32)(127 + scc.w) << 23);
      A = ((sA0 + sB0) * sc0 + (sA1 + sB1) * sc1)
        + ((sA2 + sB2) * sc2 + (sA3 + sB3) * sc3);
      logZ += C6 * (float)n;
      u32 bb = __builtin_amdgcn_readfirstlane(__float_as_uint(A));
      int ex = (int)((bb >> 23) & 255u) - 127;
      A *= __uint_as_float((u32)(127 - ex) << 23);
      logZ += (float)ex * 0.6931471805599453f;
    }
    if (k < 7) {
#pragma unroll
      for (int m = 0; m < 8; ++m) gc[m] = gn[m];
      scc = scn;
    }
  }

  float res = logZ + __logf(A);
  res = __shfl(res, 1, 64);           // EOS = 1
  if (j == 0) atomicAdd(out, res - gp);
}

extern "C" void kernel_launch(void* const* d_in, const int* in_sizes, int n_in,
                              void* d_out, int out_size, void* d_ws, size_t ws_size,
                              hipStream_t stream) {
  const float* F     = (const float*)d_in[0];   // features (S,B,D) f32
  const int*   tags  = (const int*)  d_in[1];   // (S,B) i32
  const int*   seq   = (const int*)  d_in[2];   // (B,) i32
  const float* W     = (const float*)d_in[3];   // (T,D) f32
  const float* bias  = (const float*)d_in[4];   // (T,) f32
  const float* trans = (const float*)d_in[5];   // (T,T) f32
  float* out = (float*)d_out;

  char* ws = (char*)d_ws;
  // xbuf  : 272 rows x 4096 bf16 (256 used + slack)  @ 0        (2,228,224 B)
  // Wb3   : 128 KiB                                  @ 2228224
  // Ebuf  : 8 KiB (fp16 E table)                     @ 2359296
  // Gout  : 64b x 8k x 64 x 64 bf16 = 4 MiB          @ 2367488
  // Gscale: 64 x 8 x 4 i32 = 8 KiB                   @ 6561792
  // Gpart : 64 x 8 f32 = 2 KiB                       @ 6569984  (ends 6,572,032)
  unsigned short* xbuf   = (unsigned short*)ws;
  unsigned short* Wb3    = (unsigned short*)(ws + 2228224);
  u32*            Ebuf   = (u32*)(ws + 2359296);
  unsigned short* Gout   = (unsigned short*)(ws + 2367488);
  int*            Gscale = (int*)(ws + 6561792);
  float*          Gpart  = (float*)(ws + 6569984);

  prep       <<<257, 256, 0, stream>>>(W, trans, Wb3, Ebuf, out);
  emit_gemm  <<<256, 256, 0, stream>>>(F, Wb3, bias, xbuf);
  chunk_prod <<<512, 256, 0, stream>>>(xbuf, trans, Ebuf, tags, seq, Gout, Gscale, Gpart);
  chain_apply<<<64,   64, 0, stream>>>(xbuf, trans, Gout, Gscale, Gpart, seq, out);
}